// Round 1
// baseline (323.587 us; speedup 1.0000x reference)
//
#include <hip/hip_runtime.h>
#include <hip/hip_bf16.h>

typedef _Float16 half8 __attribute__((ext_vector_type(8)));
typedef _Float16 half4v __attribute__((ext_vector_type(4)));
typedef float f32x4 __attribute__((ext_vector_type(4)));

#define SWZ(byte, r) ((unsigned)(byte) ^ ((((unsigned)(r)) & 7u) << 4))

constexpr int Bb = 128;     // batches
constexpr int Nn = 2048;    // nodes
constexpr int Ee = 128;     // embed
constexpr int BM = 64;      // rows per block in GEMM passes
constexpr int NBLK = (Bb * Nn) / BM;   // 4096

// workspace layout (bytes)
constexpr size_t OFF_W    = 0;                                   // 4 tiles x 32768 (f16, pre-swizzled)
constexpr size_t OFF_PROJ = 131072;                              // [B*N][128] f16, pre-swizzled, 64 MiB
constexpr size_t OFF_UT   = OFF_PROJ + (size_t)Bb * Nn * Ee * 2; // [B*N] f32
constexpr size_t OFF_AT   = OFF_UT  + (size_t)Bb * Nn * 4;
constexpr size_t OFF_UT2  = OFF_AT  + (size_t)Bb * Nn * 4;

// ---------------- prep: convert weights fp32 -> f16, pre-swizzled tiles ----------------
// tile 0: W_s[e][s], tile 1: W_a[f][e], tile 2: W_c1[f][e]=W_c[f][e], tile 3: W_c2[f][e]=W_c[f][128+e]
__global__ __launch_bounds__(256) void k_prep(const float* __restrict__ Ws,
                                              const float* __restrict__ Wa,
                                              const float* __restrict__ Wc,
                                              char* __restrict__ wdst)
{
    int id = blockIdx.x * 256 + threadIdx.x;
    for (int i = id; i < 65536; i += 64 * 256) {
        int mat = i >> 14;
        int rem = i & 16383;
        int r = rem >> 7, c = rem & 127;
        float v;
        if      (mat == 0) v = Ws[r * 128 + c];
        else if (mat == 1) v = Wa[r * 128 + c];
        else if (mat == 2) v = Wc[r * 256 + c];
        else               v = Wc[r * 256 + 128 + c];
        unsigned off = SWZ((unsigned)((r * 128 + c) * 2), r);
        *reinterpret_cast<_Float16*>(wdst + (size_t)mat * 32768 + off) = (_Float16)v;
    }
}

// ---------------- pass1: proj = inst @ Ws^T + bs ; u_t = v_a . tanh(proj @ Wa^T + ba) ----
__global__ __launch_bounds__(256) void k_pass1(const float* __restrict__ inst,
                                               const char* __restrict__ wtiles,
                                               const float* __restrict__ bs,
                                               const float* __restrict__ ba,
                                               const float* __restrict__ va,
                                               char* __restrict__ projg,
                                               float* __restrict__ ut)
{
    __shared__ _Float16 ldsA[BM * 128];    // 16 KB: instance tile, then proj tile (aliased)
    __shared__ _Float16 ldsW[128 * 128];   // 32 KB: W_s then W_a

    const int tid  = threadIdx.x;
    const int lane = tid & 63;
    const int w    = tid >> 6;       // wave 0..3
    const int l15  = lane & 15;
    const int kg   = lane >> 4;      // 0..3
    const size_t row0 = (size_t)blockIdx.x * BM;

    // stage instance tile: fp32 -> f16, swizzled
    {
        const float* src = inst + row0 * 128;
        #pragma unroll
        for (int i = 0; i < 8; ++i) {
            int f = i * 256 + tid;            // float4 index, 2048 total
            int r = f >> 5, c4 = f & 31;
            float4 v = *reinterpret_cast<const float4*>(src + (size_t)f * 4);
            half4v h = { (_Float16)v.x, (_Float16)v.y, (_Float16)v.z, (_Float16)v.w };
            unsigned off = SWZ((unsigned)(r * 256 + c4 * 8), r);
            *reinterpret_cast<half4v*>((char*)ldsA + off) = h;
        }
    }
    // stage W_s (raw copy of pre-swizzled tile)
    #pragma unroll
    for (int i = 0; i < 8; ++i) {
        unsigned o = (unsigned)((i * 256 + tid) * 16);
        *reinterpret_cast<uint4*>((char*)ldsW + o) =
            *reinterpret_cast<const uint4*>(wtiles + o);
    }
    __syncthreads();

    const int arow = w * 16 + l15;

    // GEMM1
    f32x4 acc[8];
    #pragma unroll
    for (int fr = 0; fr < 8; ++fr) acc[fr] = f32x4{0.f, 0.f, 0.f, 0.f};
    #pragma unroll
    for (int kk = 0; kk < 4; ++kk) {
        unsigned aoff = SWZ((unsigned)(arow * 256 + kk * 64 + kg * 16), arow);
        half8 af = *reinterpret_cast<const half8*>((char*)ldsA + aoff);
        #pragma unroll
        for (int fr = 0; fr < 8; ++fr) {
            int br = fr * 16 + l15;
            unsigned boff = SWZ((unsigned)(br * 256 + kk * 64 + kg * 16), br);
            half8 bf = *reinterpret_cast<const half8*>((char*)ldsW + boff);
            acc[fr] = __builtin_amdgcn_mfma_f32_16x16x32_f16(af, bf, acc[fr], 0, 0, 0);
        }
    }
    __syncthreads();   // GEMM1 LDS reads complete

    // write proj (f16, swizzled) into ldsA (aliased over instance tile), adding b_s
    #pragma unroll
    for (int fr = 0; fr < 8; ++fr) {
        int e = fr * 16 + l15;
        float bsv = bs[e];
        #pragma unroll
        for (int j = 0; j < 4; ++j) {
            int r = w * 16 + kg * 4 + j;
            float pv = acc[fr][j] + bsv;
            unsigned off = SWZ((unsigned)(r * 256 + e * 2), r);
            *reinterpret_cast<_Float16*>((char*)ldsA + off) = (_Float16)pv;
        }
    }
    // stage W_a
    #pragma unroll
    for (int i = 0; i < 8; ++i) {
        unsigned o = (unsigned)((i * 256 + tid) * 16);
        *reinterpret_cast<uint4*>((char*)ldsW + o) =
            *reinterpret_cast<const uint4*>(wtiles + 32768 + o);
    }
    __syncthreads();

    // copy proj tile raw -> global (stays pre-swizzled)
    {
        char* dst = projg + row0 * 256;
        #pragma unroll
        for (int i = 0; i < 4; ++i) {
            unsigned o = (unsigned)((i * 256 + tid) * 16);
            *reinterpret_cast<uint4*>(dst + o) =
                *reinterpret_cast<const uint4*>((const char*)ldsA + o);
        }
    }

    // GEMM_a + tanh + dot(v_a)
    f32x4 tac[8];
    #pragma unroll
    for (int fr = 0; fr < 8; ++fr) tac[fr] = f32x4{0.f, 0.f, 0.f, 0.f};
    #pragma unroll
    for (int kk = 0; kk < 4; ++kk) {
        unsigned aoff = SWZ((unsigned)(arow * 256 + kk * 64 + kg * 16), arow);
        half8 af = *reinterpret_cast<const half8*>((char*)ldsA + aoff);
        #pragma unroll
        for (int fr = 0; fr < 8; ++fr) {
            int br = fr * 16 + l15;
            unsigned boff = SWZ((unsigned)(br * 256 + kk * 64 + kg * 16), br);
            half8 bf = *reinterpret_cast<const half8*>((char*)ldsW + boff);
            tac[fr] = __builtin_amdgcn_mfma_f32_16x16x32_f16(af, bf, tac[fr], 0, 0, 0);
        }
    }
    float u[4] = {0.f, 0.f, 0.f, 0.f};
    #pragma unroll
    for (int fr = 0; fr < 8; ++fr) {
        int fcol = fr * 16 + l15;
        float vav = va[fcol], bav = ba[fcol];
        #pragma unroll
        for (int j = 0; j < 4; ++j)
            u[j] += vav * tanhf(tac[fr][j] + bav);
    }
    #pragma unroll
    for (int d = 1; d < 16; d <<= 1) {
        #pragma unroll
        for (int j = 0; j < 4; ++j) u[j] += __shfl_xor(u[j], d);
    }
    if (l15 == 0) {
        #pragma unroll
        for (int j = 0; j < 4; ++j)
            ut[row0 + w * 16 + kg * 4 + j] = u[j];
    }
}

// ---------------- softmax over N per batch: a_t = softmax(u_t) --------------------------
__global__ __launch_bounds__(256) void k_softmax(const float* __restrict__ x,
                                                 float* __restrict__ y)
{
    __shared__ float red[4];
    const int b = blockIdx.x, tid = threadIdx.x;
    const int lane = tid & 63, w = tid >> 6;
    const float* xb = x + (size_t)b * Nn;
    float4 v0 = *reinterpret_cast<const float4*>(xb + tid * 8);
    float4 v1 = *reinterpret_cast<const float4*>(xb + tid * 8 + 4);
    float m = fmaxf(fmaxf(fmaxf(v0.x, v0.y), fmaxf(v0.z, v0.w)),
                    fmaxf(fmaxf(v1.x, v1.y), fmaxf(v1.z, v1.w)));
    #pragma unroll
    for (int d = 1; d < 64; d <<= 1) m = fmaxf(m, __shfl_xor(m, d));
    if (lane == 0) red[w] = m;
    __syncthreads();
    float M = fmaxf(fmaxf(red[0], red[1]), fmaxf(red[2], red[3]));
    float e[8] = { expf(v0.x - M), expf(v0.y - M), expf(v0.z - M), expf(v0.w - M),
                   expf(v1.x - M), expf(v1.y - M), expf(v1.z - M), expf(v1.w - M) };
    float s = 0.f;
    #pragma unroll
    for (int i = 0; i < 8; ++i) s += e[i];
    #pragma unroll
    for (int d = 1; d < 64; d <<= 1) s += __shfl_xor(s, d);
    __syncthreads();
    if (lane == 0) red[w] = s;
    __syncthreads();
    float inv = 1.0f / (red[0] + red[1] + red[2] + red[3]);
    float* yb = y + (size_t)b * Nn;
    float4 o0 = { e[0] * inv, e[1] * inv, e[2] * inv, e[3] * inv };
    float4 o1 = { e[4] * inv, e[5] * inv, e[6] * inv, e[7] * inv };
    *reinterpret_cast<float4*>(yb + tid * 8)     = o0;
    *reinterpret_cast<float4*>(yb + tid * 8 + 4) = o1;
}

// ---------------- pass2: u_t_2 = v_c . tanh(U1 + a_t*U2 + bc) ---------------------------
__global__ __launch_bounds__(256) void k_pass2(const char* __restrict__ projg,
                                               const char* __restrict__ wtiles,
                                               const float* __restrict__ bc,
                                               const float* __restrict__ vc,
                                               const float* __restrict__ at,
                                               float* __restrict__ ut2)
{
    __shared__ _Float16 ldsP[BM * 128];    // 16 KB
    __shared__ _Float16 ldsW[128 * 128];   // 32 KB: W_c1 then W_c2

    const int tid  = threadIdx.x;
    const int lane = tid & 63;
    const int w    = tid >> 6;
    const int l15  = lane & 15;
    const int kg   = lane >> 4;
    const size_t row0 = (size_t)blockIdx.x * BM;

    // stage proj tile (raw copy, already swizzled)
    {
        const char* src = projg + row0 * 256;
        #pragma unroll
        for (int i = 0; i < 4; ++i) {
            unsigned o = (unsigned)((i * 256 + tid) * 16);
            *reinterpret_cast<uint4*>((char*)ldsP + o) =
                *reinterpret_cast<const uint4*>(src + o);
        }
    }
    // stage W_c1
    #pragma unroll
    for (int i = 0; i < 8; ++i) {
        unsigned o = (unsigned)((i * 256 + tid) * 16);
        *reinterpret_cast<uint4*>((char*)ldsW + o) =
            *reinterpret_cast<const uint4*>(wtiles + 65536 + o);
    }
    __syncthreads();

    const int arow = w * 16 + l15;
    f32x4 u1[8], u2[8];
    #pragma unroll
    for (int fr = 0; fr < 8; ++fr) u1[fr] = f32x4{0.f, 0.f, 0.f, 0.f};
    #pragma unroll
    for (int kk = 0; kk < 4; ++kk) {
        unsigned aoff = SWZ((unsigned)(arow * 256 + kk * 64 + kg * 16), arow);
        half8 af = *reinterpret_cast<const half8*>((char*)ldsP + aoff);
        #pragma unroll
        for (int fr = 0; fr < 8; ++fr) {
            int br = fr * 16 + l15;
            unsigned boff = SWZ((unsigned)(br * 256 + kk * 64 + kg * 16), br);
            half8 bf = *reinterpret_cast<const half8*>((char*)ldsW + boff);
            u1[fr] = __builtin_amdgcn_mfma_f32_16x16x32_f16(af, bf, u1[fr], 0, 0, 0);
        }
    }
    __syncthreads();  // done reading W_c1
    // stage W_c2
    #pragma unroll
    for (int i = 0; i < 8; ++i) {
        unsigned o = (unsigned)((i * 256 + tid) * 16);
        *reinterpret_cast<uint4*>((char*)ldsW + o) =
            *reinterpret_cast<const uint4*>(wtiles + 98304 + o);
    }
    __syncthreads();
    #pragma unroll
    for (int fr = 0; fr < 8; ++fr) u2[fr] = f32x4{0.f, 0.f, 0.f, 0.f};
    #pragma unroll
    for (int kk = 0; kk < 4; ++kk) {
        unsigned aoff = SWZ((unsigned)(arow * 256 + kk * 64 + kg * 16), arow);
        half8 af = *reinterpret_cast<const half8*>((char*)ldsP + aoff);
        #pragma unroll
        for (int fr = 0; fr < 8; ++fr) {
            int br = fr * 16 + l15;
            unsigned boff = SWZ((unsigned)(br * 256 + kk * 64 + kg * 16), br);
            half8 bf = *reinterpret_cast<const half8*>((char*)ldsW + boff);
            u2[fr] = __builtin_amdgcn_mfma_f32_16x16x32_f16(af, bf, u2[fr], 0, 0, 0);
        }
    }

    float aj[4];
    #pragma unroll
    for (int j = 0; j < 4; ++j) aj[j] = at[row0 + w * 16 + kg * 4 + j];
    float u[4] = {0.f, 0.f, 0.f, 0.f};
    #pragma unroll
    for (int fr = 0; fr < 8; ++fr) {
        int fcol = fr * 16 + l15;
        float vcv = vc[fcol], bcv = bc[fcol];
        #pragma unroll
        for (int j = 0; j < 4; ++j)
            u[j] += vcv * tanhf(u1[fr][j] + aj[j] * u2[fr][j] + bcv);
    }
    #pragma unroll
    for (int d = 1; d < 16; d <<= 1) {
        #pragma unroll
        for (int j = 0; j < 4; ++j) u[j] += __shfl_xor(u[j], d);
    }
    if (l15 == 0) {
        #pragma unroll
        for (int j = 0; j < 4; ++j)
            ut2[row0 + w * 16 + kg * 4 + j] = u[j];
    }
}

// ---------------- pass3: prob = softmax(u_t_2); h_i = prob.proj; MLP head ---------------
__global__ __launch_bounds__(512) void k_final(const float* __restrict__ ut2,
                                               const char* __restrict__ projg,
                                               const float* __restrict__ W1,
                                               const float* __restrict__ b1,
                                               const float* __restrict__ W2,
                                               const float* __restrict__ b2,
                                               float* __restrict__ out)
{
    __shared__ float pl[Nn];          // unnormalized exp
    __shared__ float red[8];
    __shared__ float hpart[8][128];
    __shared__ float hi[128];
    __shared__ float o1[128];

    const int b = blockIdx.x, tid = threadIdx.x;
    const int lane = tid & 63, w = tid >> 6;   // 8 waves
    const float* ub = ut2 + (size_t)b * Nn;
    float4 x = *reinterpret_cast<const float4*>(ub + tid * 4);
    float m = fmaxf(fmaxf(x.x, x.y), fmaxf(x.z, x.w));
    #pragma unroll
    for (int d = 1; d < 64; d <<= 1) m = fmaxf(m, __shfl_xor(m, d));
    if (lane == 0) red[w] = m;
    __syncthreads();
    float M = red[0];
    #pragma unroll
    for (int k = 1; k < 8; ++k) M = fmaxf(M, red[k]);
    float e0 = expf(x.x - M), e1 = expf(x.y - M), e2 = expf(x.z - M), e3 = expf(x.w - M);
    pl[tid * 4 + 0] = e0; pl[tid * 4 + 1] = e1; pl[tid * 4 + 2] = e2; pl[tid * 4 + 3] = e3;
    float s = e0 + e1 + e2 + e3;
    #pragma unroll
    for (int d = 1; d < 64; d <<= 1) s += __shfl_xor(s, d);
    __syncthreads();
    if (lane == 0) red[w] = s;
    __syncthreads();
    float S = 0.f;
    #pragma unroll
    for (int k = 0; k < 8; ++k) S += red[k];

    // h_i accumulation over nodes (unnormalized), proj is pre-swizzled f16
    const int ep = tid & 63, sl = tid >> 6;
    const char* pb = projg + (size_t)b * Nn * 256;
    float a0 = 0.f, a1 = 0.f;
    #pragma unroll 8
    for (int n = sl; n < Nn; n += 8) {
        float wgt = pl[n];
        unsigned off = SWZ((unsigned)(n * 256 + ep * 4), n);
        unsigned pk = *reinterpret_cast<const unsigned*>(pb + off);
        union { unsigned u; _Float16 h[2]; } cv; cv.u = pk;
        a0 += wgt * (float)cv.h[0];
        a1 += wgt * (float)cv.h[1];
    }
    hpart[sl][ep * 2]     = a0;
    hpart[sl][ep * 2 + 1] = a1;
    __syncthreads();
    if (tid < 128) {
        float h = 0.f;
        #pragma unroll
        for (int k = 0; k < 8; ++k) h += hpart[k][tid];
        hi[tid] = h / S;
    }
    __syncthreads();
    if (tid < 128) {
        const float* wr = W1 + tid * 128;
        float o = b1[tid];
        #pragma unroll 4
        for (int e = 0; e < 128; ++e) o += wr[e] * hi[e];
        o1[tid] = fmaxf(o, 0.f);
    }
    __syncthreads();
    if (w == 0) {
        float p = o1[lane] * W2[lane] + o1[lane + 64] * W2[lane + 64];
        #pragma unroll
        for (int d = 1; d < 64; d <<= 1) p += __shfl_xor(p, d);
        if (lane == 0) out[b] = p + b2[0];
    }
}

// ---------------------------------------------------------------------------------------
extern "C" void kernel_launch(void* const* d_in, const int* in_sizes, int n_in,
                              void* d_out, int out_size, void* d_ws, size_t ws_size,
                              hipStream_t stream)
{
    const float* inst = (const float*)d_in[0];
    const float* Ws   = (const float*)d_in[1];
    const float* bs   = (const float*)d_in[2];
    const float* Wa   = (const float*)d_in[3];
    const float* ba   = (const float*)d_in[4];
    const float* va   = (const float*)d_in[5];
    const float* Wc   = (const float*)d_in[6];
    const float* bc   = (const float*)d_in[7];
    const float* vc   = (const float*)d_in[8];
    const float* W1   = (const float*)d_in[9];
    const float* b1   = (const float*)d_in[10];
    const float* W2   = (const float*)d_in[11];
    const float* b2   = (const float*)d_in[12];
    float* out = (float*)d_out;

    char*  ws     = (char*)d_ws;
    char*  wtiles = ws + OFF_W;
    char*  projg  = ws + OFF_PROJ;
    float* ut     = (float*)(ws + OFF_UT);
    float* at     = (float*)(ws + OFF_AT);
    float* ut2    = (float*)(ws + OFF_UT2);

    hipLaunchKernelGGL(k_prep,    dim3(64),   dim3(256), 0, stream, Ws, Wa, Wc, wtiles);
    hipLaunchKernelGGL(k_pass1,   dim3(NBLK), dim3(256), 0, stream, inst, wtiles, bs, ba, va, projg, ut);
    hipLaunchKernelGGL(k_softmax, dim3(Bb),   dim3(256), 0, stream, ut, at);
    hipLaunchKernelGGL(k_pass2,   dim3(NBLK), dim3(256), 0, stream, projg, wtiles, bc, vc, at, ut2);
    hipLaunchKernelGGL(k_final,   dim3(Bb),   dim3(512), 0, stream, ut2, projg, W1, b1, W2, b2, out);
}

// Round 3
// 284.787 us; speedup vs baseline: 1.1362x; 1.1362x over previous
//
#include <hip/hip_runtime.h>
#include <hip/hip_bf16.h>

typedef _Float16 half8 __attribute__((ext_vector_type(8)));
typedef _Float16 half4v __attribute__((ext_vector_type(4)));
typedef float f32x4 __attribute__((ext_vector_type(4)));

#define SWZ(byte, r) ((unsigned)(byte) ^ ((((unsigned)(r)) & 7u) << 4))

constexpr int Bb = 128;     // batches
constexpr int Nn = 2048;    // nodes
constexpr int Ee = 128;     // embed
constexpr int BM = 64;      // rows per block in GEMM passes
constexpr int NBLK = (Bb * Nn) / BM;   // 4096

// workspace layout (bytes)
constexpr size_t OFF_W    = 0;                                   // 4 tiles x 32768 (f16, pre-swizzled)
constexpr size_t OFF_PROJ = 131072;                              // [B*N][128] f16, pre-swizzled, 64 MiB
constexpr size_t OFF_UT   = OFF_PROJ + (size_t)Bb * Nn * Ee * 2; // [B*N] f32
constexpr size_t OFF_AT   = OFF_UT   + (size_t)Bb * Nn * 4;
constexpr size_t OFF_UT2  = OFF_AT   + (size_t)Bb * Nn * 4;
constexpr size_t OFF_PROB = OFF_UT2  + (size_t)Bb * Nn * 4;
constexpr size_t OFF_HP   = OFF_PROB + (size_t)Bb * Nn * 4;      // [B][16][128] f32 partial h_i

// async global->LDS copy, 16 B per lane (wave-uniform dest base + lane*16)
__device__ __forceinline__ void cp16(void* lds, const void* g) {
    __builtin_amdgcn_global_load_lds(
        (const __attribute__((address_space(1))) unsigned int*)g,
        (__attribute__((address_space(3))) unsigned int*)lds, 16, 0, 0);
}

__device__ __forceinline__ float fast_tanh(float x) {
    // tanh(x) = 1 - 2/(1+e^{2x}); handles +-inf correctly
    float e = __expf(2.0f * x);
    return 1.0f - 2.0f * __builtin_amdgcn_rcpf(e + 1.0f);
}

// ---------------- prep: convert weights fp32 -> f16, pre-swizzled tiles ----------------
// tile 0: W_s[e][s], tile 1: W_a[f][e], tile 2: W_c1=W_c[:, :128], tile 3: W_c2=W_c[:, 128:]
__global__ __launch_bounds__(256) void k_prep(const float* __restrict__ Ws,
                                              const float* __restrict__ Wa,
                                              const float* __restrict__ Wc,
                                              char* __restrict__ wdst)
{
    int id = blockIdx.x * 256 + threadIdx.x;
    for (int i = id; i < 65536; i += 64 * 256) {
        int mat = i >> 14;
        int rem = i & 16383;
        int r = rem >> 7, c = rem & 127;
        float v;
        if      (mat == 0) v = Ws[r * 128 + c];
        else if (mat == 1) v = Wa[r * 128 + c];
        else if (mat == 2) v = Wc[r * 256 + c];
        else               v = Wc[r * 256 + 128 + c];
        unsigned off = SWZ((unsigned)((r * 128 + c) * 2), r);
        *reinterpret_cast<_Float16*>(wdst + (size_t)mat * 32768 + off) = (_Float16)v;
    }
}

// ---------------- pass1: proj = inst @ Ws^T + bs ; u_t = v_a . tanh(proj @ Wa^T + ba) ----
__global__ __launch_bounds__(256) void k_pass1(const float* __restrict__ inst,
                                               const char* __restrict__ wtiles,
                                               const float* __restrict__ bs,
                                               const float* __restrict__ ba,
                                               const float* __restrict__ va,
                                               char* __restrict__ projg,
                                               float* __restrict__ ut)
{
    __shared__ _Float16 ldsA[BM * 128];    // 16 KB: instance tile (f16), then proj tile (aliased)
    __shared__ _Float16 ldsW[128 * 128];   // 32 KB: W_s then W_a

    const int tid  = threadIdx.x;
    const int lane = tid & 63;
    const int w    = tid >> 6;       // wave 0..3
    const int l15  = lane & 15;
    const int kg   = lane >> 4;      // 0..3
    const size_t row0 = (size_t)blockIdx.x * BM;

    // T14: issue instance loads into regs FIRST (overlaps with async weight DMA)
    float4 v[8];
    {
        const float* src = inst + row0 * 128;
        #pragma unroll
        for (int i = 0; i < 8; ++i)
            v[i] = *reinterpret_cast<const float4*>(src + (size_t)(i * 256 + tid) * 4);
    }
    // async stage W_s (pre-swizzled raw copy)
    #pragma unroll
    for (int i = 0; i < 8; ++i) {
        unsigned o = (unsigned)((i * 256 + tid) * 16);
        cp16((char*)ldsW + o, wtiles + o);
    }
    // convert instance fp32->f16, swizzled write to LDS
    #pragma unroll
    for (int i = 0; i < 8; ++i) {
        int f = i * 256 + tid;            // float4 index, 2048 total
        int r = f >> 5, c4 = f & 31;
        half4v h = { (_Float16)v[i].x, (_Float16)v[i].y, (_Float16)v[i].z, (_Float16)v[i].w };
        unsigned off = SWZ((unsigned)(r * 256 + c4 * 8), r);
        *reinterpret_cast<half4v*>((char*)ldsA + off) = h;
    }
    __syncthreads();   // waits ds_writes (lgkm) + global_load_lds (vmcnt)

    const int arow = w * 16 + l15;

    // GEMM1
    f32x4 acc[8];
    #pragma unroll
    for (int fr = 0; fr < 8; ++fr) acc[fr] = f32x4{0.f, 0.f, 0.f, 0.f};
    #pragma unroll
    for (int kk = 0; kk < 4; ++kk) {
        unsigned aoff = SWZ((unsigned)(arow * 256 + kk * 64 + kg * 16), arow);
        half8 af = *reinterpret_cast<const half8*>((char*)ldsA + aoff);
        #pragma unroll
        for (int fr = 0; fr < 8; ++fr) {
            int br = fr * 16 + l15;
            unsigned boff = SWZ((unsigned)(br * 256 + kk * 64 + kg * 16), br);
            half8 bf = *reinterpret_cast<const half8*>((char*)ldsW + boff);
            acc[fr] = __builtin_amdgcn_mfma_f32_16x16x32_f16(af, bf, acc[fr], 0, 0, 0);
        }
    }
    __syncthreads();   // GEMM1 LDS reads complete

    // async stage W_a over W_s
    #pragma unroll
    for (int i = 0; i < 8; ++i) {
        unsigned o = (unsigned)((i * 256 + tid) * 16);
        cp16((char*)ldsW + o, wtiles + 32768 + o);
    }
    // write proj (f16, swizzled) into ldsA (aliased over instance tile), adding b_s
    #pragma unroll
    for (int fr = 0; fr < 8; ++fr) {
        int e = fr * 16 + l15;
        float bsv = bs[e];
        #pragma unroll
        for (int j = 0; j < 4; ++j) {
            int r = w * 16 + kg * 4 + j;
            float pv = acc[fr][j] + bsv;
            unsigned off = SWZ((unsigned)(r * 256 + e * 2), r);
            *reinterpret_cast<_Float16*>((char*)ldsA + off) = (_Float16)pv;
        }
    }
    __syncthreads();   // waits proj ds_writes + W_a DMA

    // copy proj tile raw -> global (stays pre-swizzled)
    {
        char* dst = projg + row0 * 256;
        #pragma unroll
        for (int i = 0; i < 4; ++i) {
            unsigned o = (unsigned)((i * 256 + tid) * 16);
            *reinterpret_cast<uint4*>(dst + o) =
                *reinterpret_cast<const uint4*>((const char*)ldsA + o);
        }
    }

    // GEMM_a + tanh + dot(v_a)
    f32x4 tac[8];
    #pragma unroll
    for (int fr = 0; fr < 8; ++fr) tac[fr] = f32x4{0.f, 0.f, 0.f, 0.f};
    #pragma unroll
    for (int kk = 0; kk < 4; ++kk) {
        unsigned aoff = SWZ((unsigned)(arow * 256 + kk * 64 + kg * 16), arow);
        half8 af = *reinterpret_cast<const half8*>((char*)ldsA + aoff);
        #pragma unroll
        for (int fr = 0; fr < 8; ++fr) {
            int br = fr * 16 + l15;
            unsigned boff = SWZ((unsigned)(br * 256 + kk * 64 + kg * 16), br);
            half8 bf = *reinterpret_cast<const half8*>((char*)ldsW + boff);
            tac[fr] = __builtin_amdgcn_mfma_f32_16x16x32_f16(af, bf, tac[fr], 0, 0, 0);
        }
    }
    float u[4] = {0.f, 0.f, 0.f, 0.f};
    #pragma unroll
    for (int fr = 0; fr < 8; ++fr) {
        int fcol = fr * 16 + l15;
        float vav = va[fcol], bav = ba[fcol];
        #pragma unroll
        for (int j = 0; j < 4; ++j)
            u[j] += vav * fast_tanh(tac[fr][j] + bav);
    }
    #pragma unroll
    for (int d = 1; d < 16; d <<= 1) {
        #pragma unroll
        for (int j = 0; j < 4; ++j) u[j] += __shfl_xor(u[j], d);
    }
    if (l15 == 0) {
        #pragma unroll
        for (int j = 0; j < 4; ++j)
            ut[row0 + w * 16 + kg * 4 + j] = u[j];
    }
}

// ---------------- softmax over N per batch (normalized output) --------------------------
__global__ __launch_bounds__(256) void k_softmax(const float* __restrict__ x,
                                                 float* __restrict__ y)
{
    __shared__ float red[4];
    const int b = blockIdx.x, tid = threadIdx.x;
    const int lane = tid & 63, w = tid >> 6;
    const float* xb = x + (size_t)b * Nn;
    float4 v0 = *reinterpret_cast<const float4*>(xb + tid * 8);
    float4 v1 = *reinterpret_cast<const float4*>(xb + tid * 8 + 4);
    float m = fmaxf(fmaxf(fmaxf(v0.x, v0.y), fmaxf(v0.z, v0.w)),
                    fmaxf(fmaxf(v1.x, v1.y), fmaxf(v1.z, v1.w)));
    #pragma unroll
    for (int d = 1; d < 64; d <<= 1) m = fmaxf(m, __shfl_xor(m, d));
    if (lane == 0) red[w] = m;
    __syncthreads();
    float M = fmaxf(fmaxf(red[0], red[1]), fmaxf(red[2], red[3]));
    float e[8] = { __expf(v0.x - M), __expf(v0.y - M), __expf(v0.z - M), __expf(v0.w - M),
                   __expf(v1.x - M), __expf(v1.y - M), __expf(v1.z - M), __expf(v1.w - M) };
    float s = 0.f;
    #pragma unroll
    for (int i = 0; i < 8; ++i) s += e[i];
    #pragma unroll
    for (int d = 1; d < 64; d <<= 1) s += __shfl_xor(s, d);
    __syncthreads();
    if (lane == 0) red[w] = s;
    __syncthreads();
    float inv = 1.0f / (red[0] + red[1] + red[2] + red[3]);
    float* yb = y + (size_t)b * Nn;
    float4 o0 = { e[0] * inv, e[1] * inv, e[2] * inv, e[3] * inv };
    float4 o1 = { e[4] * inv, e[5] * inv, e[6] * inv, e[7] * inv };
    *reinterpret_cast<float4*>(yb + tid * 8)     = o0;
    *reinterpret_cast<float4*>(yb + tid * 8 + 4) = o1;
}

// ---------------- pass2: u_t_2 = v_c . tanh(U1 + a_t*U2 + bc), single barrier -----------
__global__ __launch_bounds__(256) void k_pass2(const char* __restrict__ projg,
                                               const char* __restrict__ wtiles,
                                               const float* __restrict__ bc,
                                               const float* __restrict__ vc,
                                               const float* __restrict__ at,
                                               float* __restrict__ ut2)
{
    __shared__ _Float16 ldsP [BM * 128];    // 16 KB
    __shared__ _Float16 ldsW1[128 * 128];   // 32 KB
    __shared__ _Float16 ldsW2[128 * 128];   // 32 KB  (total 80 KB -> 2 blocks/CU)

    const int tid  = threadIdx.x;
    const int lane = tid & 63;
    const int w    = tid >> 6;
    const int l15  = lane & 15;
    const int kg   = lane >> 4;
    const size_t row0 = (size_t)blockIdx.x * BM;

    // all staging async, upfront
    {
        const char* src = projg + row0 * 256;
        #pragma unroll
        for (int i = 0; i < 4; ++i) {
            unsigned o = (unsigned)((i * 256 + tid) * 16);
            cp16((char*)ldsP + o, src + o);
        }
    }
    #pragma unroll
    for (int i = 0; i < 8; ++i) {
        unsigned o = (unsigned)((i * 256 + tid) * 16);
        cp16((char*)ldsW1 + o, wtiles + 65536 + o);
    }
    #pragma unroll
    for (int i = 0; i < 8; ++i) {
        unsigned o = (unsigned)((i * 256 + tid) * 16);
        cp16((char*)ldsW2 + o, wtiles + 98304 + o);
    }
    // a_t for my 4 output rows (overlaps with DMA)
    float aj[4];
    #pragma unroll
    for (int j = 0; j < 4; ++j) aj[j] = at[row0 + w * 16 + kg * 4 + j];
    __syncthreads();

    const int arow = w * 16 + l15;
    f32x4 u1[8], u2[8];
    #pragma unroll
    for (int fr = 0; fr < 8; ++fr) { u1[fr] = f32x4{0.f,0.f,0.f,0.f}; u2[fr] = f32x4{0.f,0.f,0.f,0.f}; }
    #pragma unroll
    for (int kk = 0; kk < 4; ++kk) {
        unsigned aoff = SWZ((unsigned)(arow * 256 + kk * 64 + kg * 16), arow);
        half8 af = *reinterpret_cast<const half8*>((char*)ldsP + aoff);
        #pragma unroll
        for (int fr = 0; fr < 8; ++fr) {
            int br = fr * 16 + l15;
            unsigned boff = SWZ((unsigned)(br * 256 + kk * 64 + kg * 16), br);
            half8 bf1 = *reinterpret_cast<const half8*>((char*)ldsW1 + boff);
            u1[fr] = __builtin_amdgcn_mfma_f32_16x16x32_f16(af, bf1, u1[fr], 0, 0, 0);
            half8 bf2 = *reinterpret_cast<const half8*>((char*)ldsW2 + boff);
            u2[fr] = __builtin_amdgcn_mfma_f32_16x16x32_f16(af, bf2, u2[fr], 0, 0, 0);
        }
    }

    float u[4] = {0.f, 0.f, 0.f, 0.f};
    #pragma unroll
    for (int fr = 0; fr < 8; ++fr) {
        int fcol = fr * 16 + l15;
        float vcv = vc[fcol], bcv = bc[fcol];
        #pragma unroll
        for (int j = 0; j < 4; ++j)
            u[j] += vcv * fast_tanh(u1[fr][j] + aj[j] * u2[fr][j] + bcv);
    }
    #pragma unroll
    for (int d = 1; d < 16; d <<= 1) {
        #pragma unroll
        for (int j = 0; j < 4; ++j) u[j] += __shfl_xor(u[j], d);
    }
    if (l15 == 0) {
        #pragma unroll
        for (int j = 0; j < 4; ++j)
            ut2[row0 + w * 16 + kg * 4 + j] = u[j];
    }
}

// ---------------- k_hi: partial h_i = sum_n prob[n]*proj[n,:] over 128-node chunks ------
__global__ __launch_bounds__(256) void k_hi(const float* __restrict__ prob,
                                            const char* __restrict__ projg,
                                            float* __restrict__ hpart)
{
    __shared__ float pw[128];
    __shared__ float hp[16][128];

    const int bid = blockIdx.x;
    const int b = bid >> 4, chunk = bid & 15;
    const int n0 = chunk * 128;
    const int tid = threadIdx.x;
    const int rg = tid >> 4, c16 = tid & 15;   // 16 row-groups x 16 col-chunks

    if (tid < 128) pw[tid] = prob[(size_t)b * Nn + n0 + tid];
    __syncthreads();

    const char* pb = projg + ((size_t)b * Nn + n0) * 256;
    float acc[8] = {0.f,0.f,0.f,0.f,0.f,0.f,0.f,0.f};
    #pragma unroll
    for (int it = 0; it < 8; ++it) {
        int nl = rg + it * 16;
        float wgt = pw[nl];
        unsigned off = (unsigned)(nl * 256 + ((c16 * 16) ^ ((nl & 7) << 4)));
        half8 ph = *reinterpret_cast<const half8*>(pb + off);
        #pragma unroll
        for (int j = 0; j < 8; ++j) acc[j] += wgt * (float)ph[j];
    }
    #pragma unroll
    for (int j = 0; j < 8; ++j) hp[rg][c16 * 8 + j] = acc[j];
    __syncthreads();
    if (tid < 128) {
        float s = 0.f;
        #pragma unroll
        for (int k = 0; k < 16; ++k) s += hp[k][tid];
        hpart[((size_t)b * 16 + chunk) * 128 + tid] = s;
    }
}

// ---------------- k_head: h_i reduce + MLP head -----------------------------------------
__global__ __launch_bounds__(128) void k_head(const float* __restrict__ hpart,
                                              const float* __restrict__ W1,
                                              const float* __restrict__ b1,
                                              const float* __restrict__ W2,
                                              const float* __restrict__ b2,
                                              float* __restrict__ out)
{
    __shared__ float h[128];
    __shared__ float o1[128];
    const int b = blockIdx.x, tid = threadIdx.x;

    float s = 0.f;
    #pragma unroll
    for (int c = 0; c < 16; ++c) s += hpart[((size_t)b * 16 + c) * 128 + tid];
    h[tid] = s;
    __syncthreads();

    const float* wr = W1 + tid * 128;
    float o = b1[tid];
    #pragma unroll 8
    for (int e = 0; e < 128; e += 4) {
        float4 wv = *reinterpret_cast<const float4*>(wr + e);
        o += wv.x * h[e] + wv.y * h[e+1] + wv.z * h[e+2] + wv.w * h[e+3];
    }
    o1[tid] = fmaxf(o, 0.f);
    __syncthreads();

    if (tid < 64) {
        float p = o1[tid] * W2[tid] + o1[tid + 64] * W2[tid + 64];
        #pragma unroll
        for (int d = 1; d < 64; d <<= 1) p += __shfl_xor(p, d);
        if (tid == 0) out[b] = p + b2[0];
    }
}

// ---------------------------------------------------------------------------------------
extern "C" void kernel_launch(void* const* d_in, const int* in_sizes, int n_in,
                              void* d_out, int out_size, void* d_ws, size_t ws_size,
                              hipStream_t stream)
{
    const float* inst = (const float*)d_in[0];
    const float* Ws   = (const float*)d_in[1];
    const float* bs   = (const float*)d_in[2];
    const float* Wa   = (const float*)d_in[3];
    const float* ba   = (const float*)d_in[4];
    const float* va   = (const float*)d_in[5];
    const float* Wc   = (const float*)d_in[6];
    const float* bc   = (const float*)d_in[7];
    const float* vc   = (const float*)d_in[8];
    const float* W1   = (const float*)d_in[9];
    const float* b1   = (const float*)d_in[10];
    const float* W2   = (const float*)d_in[11];
    const float* b2   = (const float*)d_in[12];
    float* out = (float*)d_out;

    char*  ws     = (char*)d_ws;
    char*  wtiles = ws + OFF_W;
    char*  projg  = ws + OFF_PROJ;
    float* ut     = (float*)(ws + OFF_UT);
    float* at     = (float*)(ws + OFF_AT);
    float* ut2    = (float*)(ws + OFF_UT2);
    float* prob   = (float*)(ws + OFF_PROB);
    float* hpart  = (float*)(ws + OFF_HP);

    hipLaunchKernelGGL(k_prep,    dim3(64),   dim3(256), 0, stream, Ws, Wa, Wc, wtiles);
    hipLaunchKernelGGL(k_pass1,   dim3(NBLK), dim3(256), 0, stream, inst, wtiles, bs, ba, va, projg, ut);
    hipLaunchKernelGGL(k_softmax, dim3(Bb),   dim3(256), 0, stream, ut, at);
    hipLaunchKernelGGL(k_pass2,   dim3(NBLK), dim3(256), 0, stream, projg, wtiles, bc, vc, at, ut2);
    hipLaunchKernelGGL(k_softmax, dim3(Bb),   dim3(256), 0, stream, ut2, prob);
    hipLaunchKernelGGL(k_hi,      dim3(Bb*16),dim3(256), 0, stream, prob, projg, hpart);
    hipLaunchKernelGGL(k_head,    dim3(Bb),   dim3(128), 0, stream, hpart, W1, b1, W2, b2, out);
}